// Round 1
// baseline (71.265 us; speedup 1.0000x reference)
//
#include <hip/hip_runtime.h>

#define EPSF 1e-6f

// Kernel 1: one 64-lane wave per (b,c) plane (1024 contiguous floats).
// Computes the 14 distinct region maxes and writes them to mx[p*16 + r].
__global__ __launch_bounds__(256) void rmac_region_max(
    const float* __restrict__ x, float* __restrict__ mx) {
  const int lane = threadIdx.x & 63;
  const int wv = threadIdx.x >> 6;
  const int p = blockIdx.x * 4 + wv;  // plane index = b*2048 + c, 0..65535
  const float4* xp = reinterpret_cast<const float4*>(x) + (size_t)p * 256;

  const int chunk = lane & 7;   // which 4-col chunk: cols c0..c0+3
  const int g = lane >> 3;      // row group: rows g, g+8, g+16, g+24
  const int c0 = chunk * 4;

  // Column-range membership of this lane's 4-col chunk (fixed across iters).
  // s2 col ranges: [0,21), [11,32).  s3 col ranges: [0,16), [8,24), [16,32).
  const bool f2a = (c0 <= 16), p2a = (c0 == 20);  // [0,21): full / only col 20 (v.x)
  const bool f2b = (c0 >= 12), p2b = (c0 == 8);   // [11,32): full / only col 11 (v.w)
  const bool f3a = (c0 <= 12);
  const bool f3b = (c0 >= 8) && (c0 <= 20);
  const bool f3c = (c0 >= 16);

  float acc[14];
#pragma unroll
  for (int i = 0; i < 14; ++i) acc[i] = -INFINITY;

#pragma unroll
  for (int t = 0; t < 4; ++t) {
    const int r = t * 8 + g;                 // row of this lane's chunk
    const float4 v = xp[t * 64 + lane];      // coalesced 1KB per wave-inst
    const float m = fmaxf(fmaxf(v.x, v.y), fmaxf(v.z, v.w));

    const float cs2a = f2a ? m : (p2a ? v.x : -INFINITY);
    const float cs2b = f2b ? m : (p2b ? v.w : -INFINITY);
    const float cs3a = f3a ? m : -INFINITY;
    const float cs3b = f3b ? m : -INFINITY;
    const float cs3c = f3c ? m : -INFINITY;

    const bool r2a = (r < 21), r2b = (r >= 11);
    const bool r3a = (r < 16), r3b = (r >= 8) && (r < 24), r3c = (r >= 16);

    acc[0] = fmaxf(acc[0], m);                               // full 32x32 (weight 2 later)
    acc[1] = fmaxf(acc[1], r2a ? cs2a : -INFINITY);          // rows[0,21) x cols[0,21)
    acc[2] = fmaxf(acc[2], r2a ? cs2b : -INFINITY);          // rows[0,21) x cols[11,32)
    acc[3] = fmaxf(acc[3], r2b ? cs2a : -INFINITY);
    acc[4] = fmaxf(acc[4], r2b ? cs2b : -INFINITY);
    acc[5] = fmaxf(acc[5], r3a ? cs3a : -INFINITY);
    acc[6] = fmaxf(acc[6], r3a ? cs3b : -INFINITY);
    acc[7] = fmaxf(acc[7], r3a ? cs3c : -INFINITY);
    acc[8] = fmaxf(acc[8], r3b ? cs3a : -INFINITY);
    acc[9] = fmaxf(acc[9], r3b ? cs3b : -INFINITY);
    acc[10] = fmaxf(acc[10], r3b ? cs3c : -INFINITY);
    acc[11] = fmaxf(acc[11], r3c ? cs3a : -INFINITY);
    acc[12] = fmaxf(acc[12], r3c ? cs3b : -INFINITY);
    acc[13] = fmaxf(acc[13], r3c ? cs3c : -INFINITY);
  }

  // 64-lane butterfly max reduce; afterwards all lanes hold all 14 maxes.
#pragma unroll
  for (int off = 32; off >= 1; off >>= 1) {
#pragma unroll
    for (int i = 0; i < 14; ++i)
      acc[i] = fmaxf(acc[i], __shfl_xor(acc[i], off, 64));
  }

  // Lane i (<14) writes region i — static-index select chain (no scratch).
  float outv = 0.0f;
#pragma unroll
  for (int i = 0; i < 14; ++i) outv = (lane == i) ? acc[i] : outv;
  if (lane < 14) mx[(size_t)p * 16 + lane] = outv;
}

// Kernel 2: one block per batch b. Sum-of-squares over C per region ->
// ninv[r] = w_r / (sqrt(ss)+eps) in LDS -> apply and write out[b*2048+c].
__global__ __launch_bounds__(256) void rmac_norm_apply(
    const float* __restrict__ mx, float* __restrict__ out) {
  const int b = blockIdx.x;
  const int tid = threadIdx.x;
  const int lane = tid & 63, wv = tid >> 6;
  const float* mb = mx + (size_t)b * 2048 * 16;

  float ss[14];
#pragma unroll
  for (int i = 0; i < 14; ++i) ss[i] = 0.0f;

  for (int k = 0; k < 8; ++k) {
    const int c = tid + k * 256;
    const float4* q = reinterpret_cast<const float4*>(mb + (size_t)c * 16);
    const float4 q0 = q[0], q1 = q[1], q2 = q[2], q3 = q[3];
    ss[0] += q0.x * q0.x;  ss[1] += q0.y * q0.y;
    ss[2] += q0.z * q0.z;  ss[3] += q0.w * q0.w;
    ss[4] += q1.x * q1.x;  ss[5] += q1.y * q1.y;
    ss[6] += q1.z * q1.z;  ss[7] += q1.w * q1.w;
    ss[8] += q2.x * q2.x;  ss[9] += q2.y * q2.y;
    ss[10] += q2.z * q2.z; ss[11] += q2.w * q2.w;
    ss[12] += q3.x * q3.x; ss[13] += q3.y * q3.y;
  }

#pragma unroll
  for (int off = 32; off >= 1; off >>= 1) {
#pragma unroll
    for (int i = 0; i < 14; ++i) ss[i] += __shfl_xor(ss[i], off, 64);
  }

  __shared__ float red[4][14];
  __shared__ float ninv[14];
  if (lane == 0) {
#pragma unroll
    for (int i = 0; i < 14; ++i) red[wv][i] = ss[i];
  }
  __syncthreads();
  if (tid < 14) {
    const float s = red[0][tid] + red[1][tid] + red[2][tid] + red[3][tid];
    const float w = (tid == 0) ? 2.0f : 1.0f;  // global region == l=1 region
    ninv[tid] = w / (sqrtf(s) + EPSF);
  }
  __syncthreads();

  for (int k = 0; k < 8; ++k) {
    const int c = tid + k * 256;
    const float4* q = reinterpret_cast<const float4*>(mb + (size_t)c * 16);
    const float4 q0 = q[0], q1 = q[1], q2 = q[2], q3 = q[3];
    float o = ninv[0] * q0.x + ninv[1] * q0.y + ninv[2] * q0.z + ninv[3] * q0.w;
    o += ninv[4] * q1.x + ninv[5] * q1.y + ninv[6] * q1.z + ninv[7] * q1.w;
    o += ninv[8] * q2.x + ninv[9] * q2.y + ninv[10] * q2.z + ninv[11] * q2.w;
    o += ninv[12] * q3.x + ninv[13] * q3.y;
    out[b * 2048 + c] = o;
  }
}

extern "C" void kernel_launch(void* const* d_in, const int* in_sizes, int n_in,
                              void* d_out, int out_size, void* d_ws, size_t ws_size,
                              hipStream_t stream) {
  const float* x = (const float*)d_in[0];
  float* out = (float*)d_out;
  float* mx = (float*)d_ws;  // 65536 * 16 floats = 4 MiB

  rmac_region_max<<<16384, 256, 0, stream>>>(x, mx);
  rmac_norm_apply<<<32, 256, 0, stream>>>(mx, out);
}

// Round 2
// 55.003 us; speedup vs baseline: 1.2957x; 1.2957x over previous
//
#include <hip/hip_runtime.h>

#define EPSF 1e-6f

// ============================ Fast path =====================================
// K1: one 64-lane wave per (b,c) plane. Lane = (g = lane>>3, c = lane&7);
// iteration t covers row 8t+g, cols [4c, 4c+4). Compute per-lane:
//   m[t]  : max of the 4 cols (band t contribution)
//   z2a   : band-2 rows 16..20 part (g<5), z2b: band-1 rows 11..15 part (g>=3)
//   E1,E2 : boundary-column maxes (col 20 at chunk 5, col 11 at chunk 2)
//           over row ranges [0,21) and [11,32)
// then reduce the 8 values over the g lane-bits (xor 8,16,32) and store
// 8 floats per chunk: mx[p][c][{m0,m1,m2,m3,z2a,z2b,E1,E2}].
__global__ __launch_bounds__(256) void k1_bandmax(
    const float* __restrict__ x, float* __restrict__ mx) {
  const int lane = threadIdx.x & 63;
  const int wv = threadIdx.x >> 6;
  const int p = blockIdx.x * 4 + wv;  // plane index, 0..65535
  const float4* xp = reinterpret_cast<const float4*>(x) + (size_t)p * 256;

  const int c = lane & 7;
  const int g = lane >> 3;
  const bool c5 = (c == 5), c2 = (c == 2);
  const bool eact = c5 || c2;
  const bool glt5 = (g < 5), gge3 = (g >= 3);

  float m[4], e[4];
#pragma unroll
  for (int t = 0; t < 4; ++t) {
    const float4 v = xp[t * 64 + lane];
    m[t] = fmaxf(fmaxf(v.x, v.y), fmaxf(v.z, v.w));
    const float ev = c5 ? v.x : v.w;  // col 20 (chunk5) / col 11 (chunk2)
    e[t] = eact ? ev : -INFINITY;
  }

  float vals[8];
  vals[0] = m[0];
  vals[1] = m[1];
  vals[2] = m[2];
  vals[3] = m[3];
  vals[4] = glt5 ? m[2] : -INFINITY;  // rows 16..20
  vals[5] = gge3 ? m[1] : -INFINITY;  // rows 11..15
  vals[6] = fmaxf(fmaxf(e[0], e[1]), glt5 ? e[2] : -INFINITY);  // rows [0,21)
  vals[7] = fmaxf(fmaxf(e[2], e[3]), gge3 ? e[1] : -INFINITY);  // rows [11,32)

  // Reduce over g bits (8,16,32); chunk bits stay per-lane.
#pragma unroll
  for (int off = 8; off <= 32; off <<= 1) {
#pragma unroll
    for (int i = 0; i < 8; ++i)
      vals[i] = fmaxf(vals[i], __shfl_xor(vals[i], off, 64));
  }

  // Lane (g,c) stores value #g of chunk c -> one fully-coalesced 256B store.
  float outv = vals[0];
#pragma unroll
  for (int i = 1; i < 8; ++i) outv = (g == i) ? vals[i] : outv;
  mx[(size_t)p * 64 + c * 8 + g] = outv;
}

// K2: 256 blocks x 256 threads, one THREAD per plane. Builds the 14 region
// maxes from the 64 stored floats, writes rm[p][16], and block-reduces the
// per-region sum-of-squares into ssp[bid][16].
__global__ __launch_bounds__(256) void k2_regions(
    const float* __restrict__ mx, float* __restrict__ rm,
    float* __restrict__ ssp) {
  const int bid = blockIdx.x;  // b = bid>>3, slice = bid&7
  const int tid = threadIdx.x;
  const int lane = tid & 63, wv = tid >> 6;
  const int p = (bid >> 3) * 2048 + (bid & 7) * 256 + tid;
  const float4* q = reinterpret_cast<const float4*>(mx) + (size_t)p * 16;

  float Mf[8], M2a[8], M2b[8], M3a[8], M3b[8], M3c[8];
  float E1c2 = -INFINITY, E1c5 = -INFINITY, E2c2 = -INFINITY, E2c5 = -INFINITY;
#pragma unroll
  for (int c = 0; c < 8; ++c) {
    const float4 a = q[2 * c];      // m0 m1 m2 m3
    const float4 b = q[2 * c + 1];  // z2a z2b E1 E2
    const float a01 = fmaxf(a.x, a.y);
    const float a23 = fmaxf(a.z, a.w);
    Mf[c] = fmaxf(a01, a23);
    M3a[c] = a01;                 // rows [0,16)
    M3c[c] = a23;                 // rows [16,32)
    M3b[c] = fmaxf(a.y, a.z);     // rows [8,24)
    M2a[c] = fmaxf(a01, b.x);     // rows [0,21)
    M2b[c] = fmaxf(a23, b.y);     // rows [11,32)
    if (c == 2) { E1c2 = b.z; E2c2 = b.w; }
    if (c == 5) { E1c5 = b.z; E2c5 = b.w; }
  }

  float r[14];
  r[0] = fmaxf(fmaxf(fmaxf(Mf[0], Mf[1]), fmaxf(Mf[2], Mf[3])),
               fmaxf(fmaxf(Mf[4], Mf[5]), fmaxf(Mf[6], Mf[7])));
  {  // scale 2, rows [0,21)
    const float a34 = fmaxf(M2a[3], M2a[4]);
    const float m04 = fmaxf(fmaxf(M2a[0], M2a[1]), fmaxf(M2a[2], a34));
    const float m37 = fmaxf(a34, fmaxf(fmaxf(M2a[5], M2a[6]), M2a[7]));
    r[1] = fmaxf(m04, E1c5);  // cols [0,21)
    r[2] = fmaxf(m37, E1c2);  // cols [11,32)
  }
  {  // scale 2, rows [11,32)
    const float a34 = fmaxf(M2b[3], M2b[4]);
    const float m04 = fmaxf(fmaxf(M2b[0], M2b[1]), fmaxf(M2b[2], a34));
    const float m37 = fmaxf(a34, fmaxf(fmaxf(M2b[5], M2b[6]), M2b[7]));
    r[3] = fmaxf(m04, E2c5);
    r[4] = fmaxf(m37, E2c2);
  }
  {  // scale 3 rows [0,16)
    const float m01 = fmaxf(M3a[0], M3a[1]), m23 = fmaxf(M3a[2], M3a[3]);
    const float m45 = fmaxf(M3a[4], M3a[5]), m67 = fmaxf(M3a[6], M3a[7]);
    r[5] = fmaxf(m01, m23); r[6] = fmaxf(m23, m45); r[7] = fmaxf(m45, m67);
  }
  {  // scale 3 rows [8,24)
    const float m01 = fmaxf(M3b[0], M3b[1]), m23 = fmaxf(M3b[2], M3b[3]);
    const float m45 = fmaxf(M3b[4], M3b[5]), m67 = fmaxf(M3b[6], M3b[7]);
    r[8] = fmaxf(m01, m23); r[9] = fmaxf(m23, m45); r[10] = fmaxf(m45, m67);
  }
  {  // scale 3 rows [16,32)
    const float m01 = fmaxf(M3c[0], M3c[1]), m23 = fmaxf(M3c[2], M3c[3]);
    const float m45 = fmaxf(M3c[4], M3c[5]), m67 = fmaxf(M3c[6], M3c[7]);
    r[11] = fmaxf(m01, m23); r[12] = fmaxf(m23, m45); r[13] = fmaxf(m45, m67);
  }

  float4* rmp = reinterpret_cast<float4*>(rm + (size_t)p * 16);
  rmp[0] = make_float4(r[0], r[1], r[2], r[3]);
  rmp[1] = make_float4(r[4], r[5], r[6], r[7]);
  rmp[2] = make_float4(r[8], r[9], r[10], r[11]);
  rmp[3] = make_float4(r[12], r[13], 0.0f, 0.0f);

  float ss[14];
#pragma unroll
  for (int i = 0; i < 14; ++i) ss[i] = r[i] * r[i];
#pragma unroll
  for (int off = 32; off >= 1; off >>= 1) {
#pragma unroll
    for (int i = 0; i < 14; ++i) ss[i] += __shfl_xor(ss[i], off, 64);
  }
  __shared__ float red[4][14];
  if (lane == 0) {
#pragma unroll
    for (int i = 0; i < 14; ++i) red[wv][i] = ss[i];
  }
  __syncthreads();
  if (tid < 14)
    ssp[bid * 16 + tid] = red[0][tid] + red[1][tid] + red[2][tid] + red[3][tid];
}

// K3: 256 blocks (b,slice): build ninv[14] from the 8 slice partials, apply.
__global__ __launch_bounds__(256) void k3_apply(
    const float* __restrict__ rm, const float* __restrict__ ssp,
    float* __restrict__ out) {
  const int bid = blockIdx.x;
  const int tid = threadIdx.x;
  const int b = bid >> 3;
  __shared__ float ninv[14];
  if (tid < 14) {
    float s = 0.0f;
#pragma unroll
    for (int sl = 0; sl < 8; ++sl) s += ssp[(b * 8 + sl) * 16 + tid];
    const float w = (tid == 0) ? 2.0f : 1.0f;  // global region == l=1 region
    ninv[tid] = w / (sqrtf(s) + EPSF);
  }
  __syncthreads();
  const int p = b * 2048 + (bid & 7) * 256 + tid;
  const float4* q = reinterpret_cast<const float4*>(rm) + (size_t)p * 4;
  const float4 q0 = q[0], q1 = q[1], q2 = q[2], q3 = q[3];
  float o = ninv[0] * q0.x + ninv[1] * q0.y + ninv[2] * q0.z + ninv[3] * q0.w;
  o += ninv[4] * q1.x + ninv[5] * q1.y + ninv[6] * q1.z + ninv[7] * q1.w;
  o += ninv[8] * q2.x + ninv[9] * q2.y + ninv[10] * q2.z + ninv[11] * q2.w;
  o += ninv[12] * q3.x + ninv[13] * q3.y;
  out[p] = o;
}

// ==================== Fallback (proven round-1 path, 4.2MB ws) ==============
__global__ __launch_bounds__(256) void rmac_region_max_fb(
    const float* __restrict__ x, float* __restrict__ mx) {
  const int lane = threadIdx.x & 63;
  const int wv = threadIdx.x >> 6;
  const int p = blockIdx.x * 4 + wv;
  const float4* xp = reinterpret_cast<const float4*>(x) + (size_t)p * 256;
  const int chunk = lane & 7;
  const int g = lane >> 3;
  const int c0 = chunk * 4;
  const bool f2a = (c0 <= 16), p2a = (c0 == 20);
  const bool f2b = (c0 >= 12), p2b = (c0 == 8);
  const bool f3a = (c0 <= 12);
  const bool f3b = (c0 >= 8) && (c0 <= 20);
  const bool f3c = (c0 >= 16);
  float acc[14];
#pragma unroll
  for (int i = 0; i < 14; ++i) acc[i] = -INFINITY;
#pragma unroll
  for (int t = 0; t < 4; ++t) {
    const int r = t * 8 + g;
    const float4 v = xp[t * 64 + lane];
    const float m = fmaxf(fmaxf(v.x, v.y), fmaxf(v.z, v.w));
    const float cs2a = f2a ? m : (p2a ? v.x : -INFINITY);
    const float cs2b = f2b ? m : (p2b ? v.w : -INFINITY);
    const float cs3a = f3a ? m : -INFINITY;
    const float cs3b = f3b ? m : -INFINITY;
    const float cs3c = f3c ? m : -INFINITY;
    const bool r2a = (r < 21), r2b = (r >= 11);
    const bool r3a = (r < 16), r3b = (r >= 8) && (r < 24), r3c = (r >= 16);
    acc[0] = fmaxf(acc[0], m);
    acc[1] = fmaxf(acc[1], r2a ? cs2a : -INFINITY);
    acc[2] = fmaxf(acc[2], r2a ? cs2b : -INFINITY);
    acc[3] = fmaxf(acc[3], r2b ? cs2a : -INFINITY);
    acc[4] = fmaxf(acc[4], r2b ? cs2b : -INFINITY);
    acc[5] = fmaxf(acc[5], r3a ? cs3a : -INFINITY);
    acc[6] = fmaxf(acc[6], r3a ? cs3b : -INFINITY);
    acc[7] = fmaxf(acc[7], r3a ? cs3c : -INFINITY);
    acc[8] = fmaxf(acc[8], r3b ? cs3a : -INFINITY);
    acc[9] = fmaxf(acc[9], r3b ? cs3b : -INFINITY);
    acc[10] = fmaxf(acc[10], r3b ? cs3c : -INFINITY);
    acc[11] = fmaxf(acc[11], r3c ? cs3a : -INFINITY);
    acc[12] = fmaxf(acc[12], r3c ? cs3b : -INFINITY);
    acc[13] = fmaxf(acc[13], r3c ? cs3c : -INFINITY);
  }
#pragma unroll
  for (int off = 32; off >= 1; off >>= 1) {
#pragma unroll
    for (int i = 0; i < 14; ++i)
      acc[i] = fmaxf(acc[i], __shfl_xor(acc[i], off, 64));
  }
  float outv = 0.0f;
#pragma unroll
  for (int i = 0; i < 14; ++i) outv = (lane == i) ? acc[i] : outv;
  if (lane < 14) mx[(size_t)p * 16 + lane] = outv;
}

__global__ __launch_bounds__(256) void rmac_norm_apply_fb(
    const float* __restrict__ mx, float* __restrict__ out) {
  const int b = blockIdx.x;
  const int tid = threadIdx.x;
  const int lane = tid & 63, wv = tid >> 6;
  const float* mb = mx + (size_t)b * 2048 * 16;
  float ss[14];
#pragma unroll
  for (int i = 0; i < 14; ++i) ss[i] = 0.0f;
  for (int k = 0; k < 8; ++k) {
    const int c = tid + k * 256;
    const float4* q = reinterpret_cast<const float4*>(mb + (size_t)c * 16);
    const float4 q0 = q[0], q1 = q[1], q2 = q[2], q3 = q[3];
    ss[0] += q0.x * q0.x;  ss[1] += q0.y * q0.y;
    ss[2] += q0.z * q0.z;  ss[3] += q0.w * q0.w;
    ss[4] += q1.x * q1.x;  ss[5] += q1.y * q1.y;
    ss[6] += q1.z * q1.z;  ss[7] += q1.w * q1.w;
    ss[8] += q2.x * q2.x;  ss[9] += q2.y * q2.y;
    ss[10] += q2.z * q2.z; ss[11] += q2.w * q2.w;
    ss[12] += q3.x * q3.x; ss[13] += q3.y * q3.y;
  }
#pragma unroll
  for (int off = 32; off >= 1; off >>= 1) {
#pragma unroll
    for (int i = 0; i < 14; ++i) ss[i] += __shfl_xor(ss[i], off, 64);
  }
  __shared__ float red[4][14];
  __shared__ float ninv[14];
  if (lane == 0) {
#pragma unroll
    for (int i = 0; i < 14; ++i) red[wv][i] = ss[i];
  }
  __syncthreads();
  if (tid < 14) {
    const float s = red[0][tid] + red[1][tid] + red[2][tid] + red[3][tid];
    const float w = (tid == 0) ? 2.0f : 1.0f;
    ninv[tid] = w / (sqrtf(s) + EPSF);
  }
  __syncthreads();
  for (int k = 0; k < 8; ++k) {
    const int c = tid + k * 256;
    const float4* q = reinterpret_cast<const float4*>(mb + (size_t)c * 16);
    const float4 q0 = q[0], q1 = q[1], q2 = q[2], q3 = q[3];
    float o = ninv[0] * q0.x + ninv[1] * q0.y + ninv[2] * q0.z + ninv[3] * q0.w;
    o += ninv[4] * q1.x + ninv[5] * q1.y + ninv[6] * q1.z + ninv[7] * q1.w;
    o += ninv[8] * q2.x + ninv[9] * q2.y + ninv[10] * q2.z + ninv[11] * q2.w;
    o += ninv[12] * q3.x + ninv[13] * q3.y;
    out[b * 2048 + c] = o;
  }
}

extern "C" void kernel_launch(void* const* d_in, const int* in_sizes, int n_in,
                              void* d_out, int out_size, void* d_ws, size_t ws_size,
                              hipStream_t stream) {
  const float* x = (const float*)d_in[0];
  float* out = (float*)d_out;

  const size_t MX_BYTES = (size_t)65536 * 64 * 4;   // 16.78 MB
  const size_t RM_BYTES = (size_t)65536 * 16 * 4;   //  4.19 MB
  const size_t SSP_BYTES = (size_t)256 * 16 * 4;    // 16 KB
  const size_t NEED = MX_BYTES + RM_BYTES + SSP_BYTES;

  if (ws_size >= NEED) {
    float* mx = (float*)d_ws;
    float* rm = (float*)((char*)d_ws + MX_BYTES);
    float* ssp = (float*)((char*)d_ws + MX_BYTES + RM_BYTES);
    k1_bandmax<<<16384, 256, 0, stream>>>(x, mx);
    k2_regions<<<256, 256, 0, stream>>>(mx, rm, ssp);
    k3_apply<<<256, 256, 0, stream>>>(rm, ssp, out);
  } else {
    float* mx = (float*)d_ws;  // 4.19 MB, proven in round 1
    rmac_region_max_fb<<<16384, 256, 0, stream>>>(x, mx);
    rmac_norm_apply_fb<<<32, 256, 0, stream>>>(mx, out);
  }
}